// Round 1
// baseline (253.929 us; speedup 1.0000x reference)
//
#include <hip/hip_runtime.h>
#include <hip/hip_bf16.h>

// NVFP4 dynamic linear:
//   x [2,2048,4096] f32, weight [4096,4096] f32, bias [4096] f32 -> out [2,2048,4096] f32
//   M = 4096, N = 4096, K = 4096
//
// Plan:
//   k0: hipMemsetAsync scalars (amax_x, amax_w) = 0
//   k1: amax reduction (grid-stride, atomicMax on float bits)
//   k2: quantize+dequantize x -> bf16 dx in ws  (exact: e2m1*e4m3 fits in bf16)
//   k3: quantize+dequantize w -> bf16 dw in ws
//   k4: bf16 MFMA GEMM (128x128 tile, BK=64, global_load_lds staging),
//       epilogue out = alpha*acc + bias
//
// ws layout: [0,8) amax bits (2 x u32) | [256, 256+32MB) dx | [+32MB) dw

typedef unsigned short u16;
typedef __bf16 bf16x8 __attribute__((ext_vector_type(8)));
typedef float f32x4 __attribute__((ext_vector_type(4)));
typedef unsigned short u16x8 __attribute__((ext_vector_type(8)));

#define GLD_LDS(gsrc, ldst)                                                     \
  __builtin_amdgcn_global_load_lds(                                             \
      (const __attribute__((address_space(1))) void*)(gsrc),                    \
      (__attribute__((address_space(3))) void*)(ldst), 16, 0, 0)

// ---------------- rounding helpers (bit-exact vs numpy RTNE) -----------------

// float -> e4m3fn -> float round trip. v >= 0, v <= ~448 (guaranteed by scale math).
__device__ __forceinline__ float round_e4m3(float v) {
  if (v < 0.015625f) {                       // subnormal range: grid step 2^-9
    return rintf(v * 512.0f) * 0.001953125f; // RTNE (v_rndne)
  }
  unsigned b = __float_as_uint(v);
  unsigned e = (b >> 23) & 0xFFu;            // v is a normal fp32 here
  float step = __uint_as_float((e - 3u) << 23); // 2^(e-127-3): 3 mantissa bits
  return rintf(v / step) * step;             // exact pow2 div/mul, RTNE on grid
}

// round to signed E2M1 grid {0,.5,1,1.5,2,3,4,6}, RTNE, matching the reference's
// step selection (step=.5 for |a|<2, 1 for [2,4), 2 above; clamp at 6).
__device__ __forceinline__ float round_e2m1(float v) {
  float a = fabsf(v);
  float step = (a < 2.0f) ? 0.5f : ((a < 4.0f) ? 1.0f : 2.0f);
  float q = fminf(rintf(a / step) * step, 6.0f);
  return copysignf(q, v);
}

// ---------------- kernel 1: global amax of |x| and |w| ----------------------

__global__ void nvfp4_amax_kernel(const float* __restrict__ x,
                                  const float* __restrict__ w,
                                  unsigned* __restrict__ sc, int nx4, int nw4) {
  const float4* src = blockIdx.y ? (const float4*)w : (const float4*)x;
  int n4 = blockIdx.y ? nw4 : nx4;
  float m = 0.f;
  for (int i = blockIdx.x * blockDim.x + threadIdx.x; i < n4;
       i += gridDim.x * blockDim.x) {
    float4 v = src[i];
    m = fmaxf(m, fmaxf(fmaxf(fabsf(v.x), fabsf(v.y)),
                       fmaxf(fabsf(v.z), fabsf(v.w))));
  }
#pragma unroll
  for (int off = 32; off; off >>= 1) m = fmaxf(m, __shfl_down(m, off));
  __shared__ float red[4];
  if ((threadIdx.x & 63) == 0) red[threadIdx.x >> 6] = m;
  __syncthreads();
  if (threadIdx.x == 0) {
    m = fmaxf(fmaxf(red[0], red[1]), fmaxf(red[2], red[3]));
    atomicMax(&sc[blockIdx.y], __float_as_uint(m)); // positive floats order as uints
  }
}

// ------------- kernel 2/3: quantize->dequantize to bf16 ---------------------
// one thread = one 16-elem NVFP4 block along K

__global__ void nvfp4_quant_kernel(const float* __restrict__ src,
                                   u16* __restrict__ dst,
                                   const unsigned* __restrict__ sc, int which,
                                   int nblk) {
  int idx = blockIdx.x * blockDim.x + threadIdx.x;
  if (idx >= nblk) return;
  float amax = fmaxf(__uint_as_float(sc[which]), 1e-12f);
  float gs = 2688.0f / amax; // QUANT_RANGE / amax, fp32 div like reference

  float4 v[4];
  const float4* p = (const float4*)src + (size_t)idx * 4;
  v[0] = p[0]; v[1] = p[1]; v[2] = p[2]; v[3] = p[3];
  const float* fv = (const float*)v;

  float bamax = 0.f;
#pragma unroll
  for (int i = 0; i < 16; ++i) bamax = fmaxf(bamax, fabsf(fv[i]));

  float sf = round_e4m3((bamax * gs) / 6.0f); // same op order as reference
  float sfs = fmaxf(sf, 1e-12f);
  float r = gs / sfs;

  u16 ob[16];
#pragma unroll
  for (int i = 0; i < 16; ++i) {
    float q = round_e2m1(fv[i] * r);
    float d = q * sf;                      // exact in bf16 (<=6 significand bits)
    ob[i] = (u16)(__float_as_uint(d) >> 16); // exact truncation (low bits are 0)
  }
  u16x8* o = (u16x8*)(dst + (size_t)idx * 16);
  o[0] = *(u16x8*)ob;
  o[1] = *(u16x8*)(ob + 8);
}

// ---------------- kernel 4: bf16 GEMM, out = alpha*(dx @ dw^T) + bias -------
// 128x128 tile, BK=64, 256 threads = 4 waves (2x2), each wave 64x64 output.

__global__ __launch_bounds__(256) void nvfp4_gemm_kernel(
    const u16* __restrict__ A,   // dx [M][K] bf16 bits
    const u16* __restrict__ B,   // dw [N][K] bf16 bits (B^T layout)
    const float* __restrict__ bias, const unsigned* __restrict__ sc,
    float* __restrict__ C, int M, int N, int K) {
  __shared__ u16 lA[128 * 64];
  __shared__ u16 lB[128 * 64];

  const int tid = threadIdx.x;
  const int lane = tid & 63;
  const int wv = tid >> 6;       // wave 0..3
  const int wm = wv >> 1, wn = wv & 1;
  const int tm0 = blockIdx.y * 128, tn0 = blockIdx.x * 128;

  const int srow = lane >> 3;         // staging: 8 rows x 8 lanes per chunk
  const int scol = (lane & 7) * 8;    // 8 bf16 = 16B per lane
  const int rb = lane & 15;           // fragment row within 16
  const int koff = (lane >> 4) * 8;   // assumed k-mapping (same for A and B ->
                                      // result invariant to the true intra-K map)
  f32x4 acc[4][4] = {};

  for (int k0 = 0; k0 < K; k0 += 64) {
#pragma unroll
    for (int c = 0; c < 4; ++c) {
      int ch = wv * 4 + c;            // 1KB LDS chunk per wave-call
      int row = ch * 8 + srow;
      GLD_LDS(A + (size_t)(tm0 + row) * K + k0 + scol, lA + ch * 512);
      GLD_LDS(B + (size_t)(tn0 + row) * K + k0 + scol, lB + ch * 512);
    }
    __syncthreads();                  // compiler drains vmcnt before barrier
#pragma unroll
    for (int kh = 0; kh < 2; ++kh) {
      bf16x8 av[4], bv[4];
#pragma unroll
      for (int i = 0; i < 4; ++i)
        av[i] = *(const bf16x8*)(lA + (wm * 64 + i * 16 + rb) * 64 + kh * 32 + koff);
#pragma unroll
      for (int i = 0; i < 4; ++i)
        bv[i] = *(const bf16x8*)(lB + (wn * 64 + i * 16 + rb) * 64 + kh * 32 + koff);
#pragma unroll
      for (int i = 0; i < 4; ++i)
#pragma unroll
        for (int j = 0; j < 4; ++j)
          acc[i][j] = __builtin_amdgcn_mfma_f32_16x16x32_bf16(av[i], bv[j],
                                                              acc[i][j], 0, 0, 0);
    }
    __syncthreads();
  }

  float ax = fmaxf(__uint_as_float(sc[0]), 1e-12f);
  float aw = fmaxf(__uint_as_float(sc[1]), 1e-12f);
  float alpha = (ax * aw) / 7225344.0f;   // / QUANT_RANGE^2 (exact constant)

  const int orow = (lane >> 4) * 4;       // C/D layout: col=lane&15,
  const int ocol = lane & 15;             // row=(lane>>4)*4+reg  [m89-verified]
#pragma unroll
  for (int i = 0; i < 4; ++i) {
#pragma unroll
    for (int j = 0; j < 4; ++j) {
      int col = tn0 + wn * 64 + j * 16 + ocol;
      float bvv = bias[col];
#pragma unroll
      for (int rr = 0; rr < 4; ++rr) {
        int row = tm0 + wm * 64 + i * 16 + orow + rr;
        C[(size_t)row * N + col] = alpha * acc[i][j][rr] + bvv;
      }
    }
  }
}

// ---------------------------------------------------------------------------

extern "C" void kernel_launch(void* const* d_in, const int* in_sizes, int n_in,
                              void* d_out, int out_size, void* d_ws, size_t ws_size,
                              hipStream_t stream) {
  const float* x = (const float*)d_in[0];
  const float* w = (const float*)d_in[1];
  const float* bias = (const float*)d_in[2];
  float* out = (float*)d_out;

  const int N = in_sizes[2];             // 4096 (out_features)
  const int K = in_sizes[1] / N;         // 4096 (in_features)
  const int M = in_sizes[0] / K;         // 4096 (2*2048)

  unsigned char* ws = (unsigned char*)d_ws;
  unsigned* sc = (unsigned*)ws;                                // 2 amax scalars
  u16* dx = (u16*)(ws + 256);                                  // 32 MB
  u16* dw = (u16*)(ws + 256 + (size_t)M * K * sizeof(u16));    // 32 MB

  hipMemsetAsync(sc, 0, 8, stream);

  nvfp4_amax_kernel<<<dim3(256, 2), 256, 0, stream>>>(x, w, sc, M * K / 4,
                                                      N * K / 4);

  int nbx = M * K / 16, nbw = N * K / 16;
  nvfp4_quant_kernel<<<(nbx + 255) / 256, 256, 0, stream>>>(x, dx, sc, 0, nbx);
  nvfp4_quant_kernel<<<(nbw + 255) / 256, 256, 0, stream>>>(w, dw, sc, 1, nbw);

  nvfp4_gemm_kernel<<<dim3(N / 128, M / 128), 256, 0, stream>>>(dx, dw, bias, sc,
                                                                out, M, N, K);
}

// Round 2
// 194.952 us; speedup vs baseline: 1.3025x; 1.3025x over previous
//
#include <hip/hip_runtime.h>
#include <hip/hip_bf16.h>

// NVFP4 dynamic linear: x[2,2048,4096] f32, w[4096,4096] f32, bias[4096] -> out f32
// M=4096, N=4096, K=4096.
//
// Pipeline: amax -> quant/dequant to bf16 (exact: e2m1*e4m3 products fit bf16,
// accumulate fp32) -> 256x256-tile bf16 MFMA GEMM with counted-vmcnt 3-deep
// software pipeline (T1+T2+T3+T4+T5 stack), epilogue alpha*acc + bias.
//
// ws: [0,8) amax bits | [256, +32MB) dx bf16 | [+32MB) dw bf16

typedef unsigned short u16;
typedef __bf16 bf16x8 __attribute__((ext_vector_type(8)));
typedef float f32x4 __attribute__((ext_vector_type(4)));
typedef unsigned short u16x8 __attribute__((ext_vector_type(8)));

#define GLD_LDS(gsrc, ldst)                                                     \
  __builtin_amdgcn_global_load_lds(                                             \
      (const __attribute__((address_space(1))) void*)(gsrc),                    \
      (__attribute__((address_space(3))) void*)(ldst), 16, 0, 0)

#define SBAR()                                                                  \
  do {                                                                          \
    asm volatile("" ::: "memory");                                              \
    __builtin_amdgcn_s_barrier();                                               \
    asm volatile("" ::: "memory");                                              \
  } while (0)

// ---------------- rounding helpers (bit-exact vs numpy RTNE) -----------------

__device__ __forceinline__ float round_e4m3(float v) {
  if (v < 0.015625f) {                        // subnormal grid, step 2^-9
    return rintf(v * 512.0f) * 0.001953125f;
  }
  unsigned b = __float_as_uint(v);
  unsigned e = (b >> 23) & 0xFFu;
  float step = __uint_as_float((e - 3u) << 23); // 2^(e-127-3)
  return rintf(v / step) * step;
}

__device__ __forceinline__ float round_e2m1(float v) {
  float a = fabsf(v);
  float step = (a < 2.0f) ? 0.5f : ((a < 4.0f) ? 1.0f : 2.0f);
  float q = fminf(rintf(a / step) * step, 6.0f);
  return copysignf(q, v);
}

// ---------------- kernel 1: global amax of |x| and |w| ----------------------

__global__ void nvfp4_amax_kernel(const float* __restrict__ x,
                                  const float* __restrict__ w,
                                  unsigned* __restrict__ sc, int nx4, int nw4) {
  const float4* src = blockIdx.y ? (const float4*)w : (const float4*)x;
  int n4 = blockIdx.y ? nw4 : nx4;
  float m = 0.f;
  for (int i = blockIdx.x * blockDim.x + threadIdx.x; i < n4;
       i += gridDim.x * blockDim.x) {
    float4 v = src[i];
    m = fmaxf(m, fmaxf(fmaxf(fabsf(v.x), fabsf(v.y)),
                       fmaxf(fabsf(v.z), fabsf(v.w))));
  }
#pragma unroll
  for (int off = 32; off; off >>= 1) m = fmaxf(m, __shfl_down(m, off));
  __shared__ float red[4];
  if ((threadIdx.x & 63) == 0) red[threadIdx.x >> 6] = m;
  __syncthreads();
  if (threadIdx.x == 0) {
    m = fmaxf(fmaxf(red[0], red[1]), fmaxf(red[2], red[3]));
    atomicMax(&sc[blockIdx.y], __float_as_uint(m));
  }
}

// ------------- kernel 2/3: quantize->dequantize to bf16 ---------------------

__global__ void nvfp4_quant_kernel(const float* __restrict__ src,
                                   u16* __restrict__ dst,
                                   const unsigned* __restrict__ sc, int which,
                                   int nblk) {
  int idx = blockIdx.x * blockDim.x + threadIdx.x;
  if (idx >= nblk) return;
  float amax = fmaxf(__uint_as_float(sc[which]), 1e-12f);
  float gs = 2688.0f / amax;

  float4 v[4];
  const float4* p = (const float4*)src + (size_t)idx * 4;
  v[0] = p[0]; v[1] = p[1]; v[2] = p[2]; v[3] = p[3];
  const float* fv = (const float*)v;

  float bamax = 0.f;
#pragma unroll
  for (int i = 0; i < 16; ++i) bamax = fmaxf(bamax, fabsf(fv[i]));

  float sf = round_e4m3((bamax * gs) / 6.0f);
  float sfs = fmaxf(sf, 1e-12f);
  float r = gs / sfs;

  u16 ob[16];
#pragma unroll
  for (int i = 0; i < 16; ++i) {
    float q = round_e2m1(fv[i] * r);
    float d = q * sf;                        // exact in bf16
    ob[i] = (u16)(__float_as_uint(d) >> 16);
  }
  u16x8* o = (u16x8*)(dst + (size_t)idx * 16);
  o[0] = *(u16x8*)ob;
  o[1] = *(u16x8*)(ob + 8);
}

// ---------------- kernel 4: 256x256 bf16 GEMM, counted-vmcnt pipeline -------
// 512 threads = 8 waves (2 M x 4 N), per-wave 128x64 output = acc[8][4].
// BK=32 (one 16x16x32 MFMA per frag pair per K-tile), 3-deep LDS ring.
// Schedule per K-tile (group t), buffers b=t%3:
//   phase0: ds_read av(mh=0)+bv; stage A(t+2); SBAR; 16 MFMA; SBAR
//   phase1: ds_read av(mh=1);    stage B(t+2); SBAR; 16 MFMA; vmcnt(4); SBAR
// vmcnt(4) before the closing barrier => tile t+1 resident for group t+1
// (4 = loads in flight for tile t+2). Never 0 except the tail.

#define BM 256
#define BN 256
#define BK 32

__global__ __launch_bounds__(512, 2) void nvfp4_gemm_kernel(
    const u16* __restrict__ A,   // dx [M][K]
    const u16* __restrict__ B,   // dw [N][K]
    const float* __restrict__ bias, const unsigned* __restrict__ sc,
    float* __restrict__ C, int M, int N, int K) {
  __shared__ u16 lA[3][BM * BK];
  __shared__ u16 lB[3][BN * BK];

  const int tid = threadIdx.x;
  const int lane = tid & 63;
  const int wv = tid >> 6;
  const int wm = wv >> 2;        // 0..1
  const int wn = wv & 3;         // 0..3

  // T1: XCD-aware swizzle. 256 blocks, 8 XCDs x 32; each XCD owns a 4x8 tile
  // region of the 16x16 tile grid (bijective since 256 % 8 == 0).
  const int bid = blockIdx.x;
  const int xcd = bid & 7, loc = bid >> 3;
  const int tm0 = ((xcd & 3) * 4 + (loc & 3)) * BM;
  const int tn0 = ((xcd >> 2) * 8 + (loc >> 2)) * BN;

  // ---- staging addressing (pre-swizzled global source, linear LDS dest) ----
  const int srow = tid >> 2;                 // 0..127
  const int skey = (srow >> 1) & 3;          // same key for row and row+128
  const int scol = ((tid & 3) ^ skey) * 8;   // swizzled 8-elem slot
  const u16* gA0 = A + (size_t)(tm0 + srow) * K + scol;
  const u16* gA1 = A + (size_t)(tm0 + 128 + srow) * K + scol;
  const u16* gB0 = B + (size_t)(tn0 + srow) * K + scol;
  const u16* gB1 = B + (size_t)(tn0 + 128 + srow) * K + scol;
  const int ld0 = tid * 8;                   // LDS element offsets (linear)
  const int ld1 = tid * 8 + 4096;

#define STAGE_A(bc, kt)                                                         \
  do {                                                                          \
    GLD_LDS(gA0 + (size_t)(kt) * BK, &lA[bc][ld0]);                             \
    GLD_LDS(gA1 + (size_t)(kt) * BK, &lA[bc][ld1]);                             \
  } while (0)
#define STAGE_B(bc, kt)                                                         \
  do {                                                                          \
    GLD_LDS(gB0 + (size_t)(kt) * BK, &lB[bc][ld0]);                             \
    GLD_LDS(gB1 + (size_t)(kt) * BK, &lB[bc][ld1]);                             \
  } while (0)

  // ---- fragment addressing (T2 swizzle on the read side, same involution) --
  const int rb = lane & 15;
  const int cc = (((lane >> 4) ^ ((rb >> 1) & 3)) << 3); // thread-const slot
  const int arow = wm * 128 + rb;            // + mh*64 + i*16
  const int brow = wn * 64 + rb;             // + j*16

  f32x4 acc[8][4] = {};
  const int NT = K / BK;                     // 128

  // prologue: stage tiles 0 and 1; make tile 0 resident
  STAGE_A(0, 0); STAGE_B(0, 0);
  STAGE_A(1, 1); STAGE_B(1, 1);
  asm volatile("s_waitcnt vmcnt(4)" ::: "memory");
  SBAR();

  int bc = 0;
  for (int t = 0; t < NT; ++t) {
    int b2 = bc + 2; if (b2 >= 3) b2 -= 3;
    const u16* bufA = lA[bc];
    const u16* bufB = lB[bc];
    const bool st = (t + 2 < NT);

    // ---------------- phase 0 (mh = 0) + B frags for both phases ----------
    bf16x8 av[4], bv[4];
#pragma unroll
    for (int i = 0; i < 4; ++i)
      av[i] = *(const bf16x8*)(bufA + (arow + i * 16) * BK + cc);
#pragma unroll
    for (int j = 0; j < 4; ++j)
      bv[j] = *(const bf16x8*)(bufB + (brow + j * 16) * BK + cc);
    if (st) STAGE_A(b2, t + 2);
    SBAR();
    __builtin_amdgcn_s_setprio(1);
#pragma unroll
    for (int i = 0; i < 4; ++i)
#pragma unroll
      for (int j = 0; j < 4; ++j)
        acc[i][j] = __builtin_amdgcn_mfma_f32_16x16x32_bf16(av[i], bv[j],
                                                            acc[i][j], 0, 0, 0);
    __builtin_amdgcn_s_setprio(0);
    SBAR();

    // ---------------- phase 1 (mh = 1) ------------------------------------
    bf16x8 aw[4];
#pragma unroll
    for (int i = 0; i < 4; ++i)
      aw[i] = *(const bf16x8*)(bufA + (arow + 64 + i * 16) * BK + cc);
    if (st) STAGE_B(b2, t + 2);
    SBAR();
    __builtin_amdgcn_s_setprio(1);
#pragma unroll
    for (int i = 0; i < 4; ++i)
#pragma unroll
      for (int j = 0; j < 4; ++j)
        acc[4 + i][j] = __builtin_amdgcn_mfma_f32_16x16x32_bf16(aw[i], bv[j],
                                                                acc[4 + i][j],
                                                                0, 0, 0);
    __builtin_amdgcn_s_setprio(0);
    // counted drain: tile t+1 must be resident for the next group. Loads
    // younger than tile t+1's are tile t+2's (4 if staged this group).
    if (st) asm volatile("s_waitcnt vmcnt(4)" ::: "memory");
    else    asm volatile("s_waitcnt vmcnt(0)" ::: "memory");
    SBAR();

    bc = bc + 1 == 3 ? 0 : bc + 1;
  }

  // ---------------- epilogue: out = alpha*acc + bias ------------------------
  float ax = fmaxf(__uint_as_float(sc[0]), 1e-12f);
  float aw_ = fmaxf(__uint_as_float(sc[1]), 1e-12f);
  float alpha = (ax * aw_) / 7225344.0f;     // amax_x*amax_w / 2688^2

  const int orow = (lane >> 4) * 4;          // C/D: col=lane&15, row=(lane>>4)*4+reg
  const int ocol = lane & 15;
#pragma unroll
  for (int ai = 0; ai < 8; ++ai) {
#pragma unroll
    for (int j = 0; j < 4; ++j) {
      int col = tn0 + wn * 64 + j * 16 + ocol;
      float bvv = bias[col];
#pragma unroll
      for (int rr = 0; rr < 4; ++rr) {
        int row = tm0 + wm * 128 + ai * 16 + orow + rr;
        C[(size_t)row * N + col] = alpha * acc[ai][j][rr] + bvv;
      }
    }
  }
#undef STAGE_A
#undef STAGE_B
}

// ---------------------------------------------------------------------------

extern "C" void kernel_launch(void* const* d_in, const int* in_sizes, int n_in,
                              void* d_out, int out_size, void* d_ws, size_t ws_size,
                              hipStream_t stream) {
  const float* x = (const float*)d_in[0];
  const float* w = (const float*)d_in[1];
  const float* bias = (const float*)d_in[2];
  float* out = (float*)d_out;

  const int N = in_sizes[2];
  const int K = in_sizes[1] / N;
  const int M = in_sizes[0] / K;

  unsigned char* ws = (unsigned char*)d_ws;
  unsigned* sc = (unsigned*)ws;
  u16* dx = (u16*)(ws + 256);
  u16* dw = (u16*)(ws + 256 + (size_t)M * K * sizeof(u16));

  hipMemsetAsync(sc, 0, 8, stream);

  nvfp4_amax_kernel<<<dim3(256, 2), 256, 0, stream>>>(x, w, sc, M * K / 4,
                                                      N * K / 4);

  int nbx = M * K / 16, nbw = N * K / 16;
  nvfp4_quant_kernel<<<(nbx + 255) / 256, 256, 0, stream>>>(x, dx, sc, 0, nbx);
  nvfp4_quant_kernel<<<(nbw + 255) / 256, 256, 0, stream>>>(w, dw, sc, 1, nbw);

  nvfp4_gemm_kernel<<<dim3((M / BM) * (N / BN)), 512, 0, stream>>>(
      dx, dw, bias, sc, out, M, N, K);
}

// Round 3
// 186.026 us; speedup vs baseline: 1.3650x; 1.0480x over previous
//
#include <hip/hip_runtime.h>
#include <hip/hip_bf16.h>

// NVFP4 dynamic linear: x[2,2048,4096] f32, w[4096,4096] f32, bias[4096] -> out f32
// M=4096, N=4096, K=4096.
//
// amax -> quant/dequant to bf16 (exact: e2m1 code x e4m3 scale fits bf16;
// products accumulate exactly in fp32 MFMA) -> 256x256 bf16 MFMA GEMM,
// ring-4 LDS pipeline with counted vmcnt(8) (4-phase slack), epilogue
// alpha*acc + bias.
//
// ws: [0,8) amax bits | [256, +32MB) dx bf16 | [+32MB) dw bf16

typedef unsigned short u16;
typedef __bf16 bf16x8 __attribute__((ext_vector_type(8)));
typedef float f32x4 __attribute__((ext_vector_type(4)));
typedef unsigned short u16x8 __attribute__((ext_vector_type(8)));

#define GLD_LDS(gsrc, ldst)                                                     \
  __builtin_amdgcn_global_load_lds(                                             \
      (const __attribute__((address_space(1))) void*)(gsrc),                    \
      (__attribute__((address_space(3))) void*)(ldst), 16, 0, 0)

#define SBAR()                                                                  \
  do {                                                                          \
    asm volatile("" ::: "memory");                                              \
    __builtin_amdgcn_s_barrier();                                               \
    asm volatile("" ::: "memory");                                              \
  } while (0)

// ---------------- rounding helpers (bit-exact vs numpy RTNE) -----------------

__device__ __forceinline__ float round_e4m3(float v) {
  if (v < 0.015625f) {                        // subnormal grid, step 2^-9
    return rintf(v * 512.0f) * 0.001953125f;
  }
  unsigned b = __float_as_uint(v);
  unsigned e = (b >> 23) & 0xFFu;
  float step = __uint_as_float((e - 3u) << 23); // 2^(e-127-3)
  return rintf(v / step) * step;
}

__device__ __forceinline__ float round_e2m1(float v) {
  float a = fabsf(v);
  float step = (a < 2.0f) ? 0.5f : ((a < 4.0f) ? 1.0f : 2.0f);
  float q = fminf(rintf(a / step) * step, 6.0f);
  return copysignf(q, v);
}

// ---------------- kernel 1: global amax of |x| and |w| ----------------------

__global__ void nvfp4_amax_kernel(const float* __restrict__ x,
                                  const float* __restrict__ w,
                                  unsigned* __restrict__ sc, int nx4, int nw4) {
  const float4* src = blockIdx.y ? (const float4*)w : (const float4*)x;
  int n4 = blockIdx.y ? nw4 : nx4;
  float m = 0.f;
  for (int i = blockIdx.x * blockDim.x + threadIdx.x; i < n4;
       i += gridDim.x * blockDim.x) {
    float4 v = src[i];
    m = fmaxf(m, fmaxf(fmaxf(fabsf(v.x), fabsf(v.y)),
                       fmaxf(fabsf(v.z), fabsf(v.w))));
  }
#pragma unroll
  for (int off = 32; off; off >>= 1) m = fmaxf(m, __shfl_down(m, off));
  __shared__ float red[4];
  if ((threadIdx.x & 63) == 0) red[threadIdx.x >> 6] = m;
  __syncthreads();
  if (threadIdx.x == 0) {
    m = fmaxf(fmaxf(red[0], red[1]), fmaxf(red[2], red[3]));
    atomicMax(&sc[blockIdx.y], __float_as_uint(m));
  }
}

// ------------- kernel 2/3: quantize->dequantize to bf16 ---------------------

__global__ void nvfp4_quant_kernel(const float* __restrict__ src,
                                   u16* __restrict__ dst,
                                   const unsigned* __restrict__ sc, int which,
                                   int nblk) {
  int idx = blockIdx.x * blockDim.x + threadIdx.x;
  if (idx >= nblk) return;
  float amax = fmaxf(__uint_as_float(sc[which]), 1e-12f);
  float gs = 2688.0f / amax;

  float4 v[4];
  const float4* p = (const float4*)src + (size_t)idx * 4;
  v[0] = p[0]; v[1] = p[1]; v[2] = p[2]; v[3] = p[3];
  const float* fv = (const float*)v;

  float bamax = 0.f;
#pragma unroll
  for (int i = 0; i < 16; ++i) bamax = fmaxf(bamax, fabsf(fv[i]));

  float sf = round_e4m3((bamax * gs) / 6.0f);
  float sfs = fmaxf(sf, 1e-12f);
  float r = gs / sfs;

  u16 ob[16];
#pragma unroll
  for (int i = 0; i < 16; ++i) {
    float q = round_e2m1(fv[i] * r);
    float d = q * sf;                        // exact in bf16
    ob[i] = (u16)(__float_as_uint(d) >> 16);
  }
  u16x8* o = (u16x8*)(dst + (size_t)idx * 16);
  o[0] = *(u16x8*)ob;
  o[1] = *(u16x8*)(ob + 8);
}

// ---------------- kernel 4: 256x256 bf16 GEMM, ring-4 pipeline --------------
// 512 threads = 8 waves (2M x 4N), per-wave 128x64 = acc[8][4]. BK=32.
// Ring of 4 K-tile buffers (128 KiB). Group = 2 K-tiles = 4 phases; each
// phase: {ds_read frags; stage one half-unit (A or B) of a future tile;
// barrier; lgkm; 16 MFMA; [vmcnt(8)]; barrier}. Stage units in issue order
// A(0),B(0),A(1),B(1),... ; unit of tile T goes to buf T&3, issued only
// after tile T-4's reads are done (WAR via group structure). Two waits per
// group, both vmcnt(8): min issue->require slack = 4 phases (vs 2 before).

#define BM 256
#define BN 256
#define BK 32

__global__ __launch_bounds__(512, 2) void nvfp4_gemm_kernel(
    const u16* __restrict__ A,   // dx [M][K]
    const u16* __restrict__ B,   // dw [N][K]
    const float* __restrict__ bias, const unsigned* __restrict__ sc,
    float* __restrict__ C, int M, int N, int K) {
  __shared__ u16 lA[4][BM * BK];
  __shared__ u16 lB[4][BN * BK];

  const int tid = threadIdx.x;
  const int lane = tid & 63;
  const int wv = tid >> 6;
  const int wm = wv >> 2;        // 0..1
  const int wn = wv & 3;         // 0..3

  // T1: XCD-aware swizzle (256 blocks, 8 XCDs x 32; 4x8 tile region per XCD)
  const int bid = blockIdx.x;
  const int xcd = bid & 7, loc = bid >> 3;
  const int tm0 = ((xcd & 3) * 4 + (loc & 3)) * BM;
  const int tn0 = ((xcd >> 2) * 8 + (loc >> 2)) * BN;

  // ---- staging addressing (pre-swizzled global source, linear LDS dest) ----
  const int srow = tid >> 2;                 // 0..127
  const int skey = (srow >> 1) & 3;
  const int scol = ((tid & 3) ^ skey) * 8;   // swizzled 8-elem slot
  const u16* gA0 = A + (size_t)(tm0 + srow) * K + scol;
  const u16* gA1 = A + (size_t)(tm0 + 128 + srow) * K + scol;
  const u16* gB0 = B + (size_t)(tn0 + srow) * K + scol;
  const u16* gB1 = B + (size_t)(tn0 + 128 + srow) * K + scol;
  const int ld0 = tid * 8;
  const int ld1 = tid * 8 + 4096;

#define STAGE_A(tt)                                                             \
  do {                                                                          \
    int _b = (tt) & 3;                                                          \
    GLD_LDS(gA0 + (size_t)(tt) * BK, &lA[_b][ld0]);                             \
    GLD_LDS(gA1 + (size_t)(tt) * BK, &lA[_b][ld1]);                             \
  } while (0)
#define STAGE_B(tt)                                                             \
  do {                                                                          \
    int _b = (tt) & 3;                                                          \
    GLD_LDS(gB0 + (size_t)(tt) * BK, &lB[_b][ld0]);                             \
    GLD_LDS(gB1 + (size_t)(tt) * BK, &lB[_b][ld1]);                             \
  } while (0)

  // ---- fragment addressing (T2 swizzle on read side, same involution) ------
  const int rb = lane & 15;
  const int cc = (((lane >> 4) ^ ((rb >> 1) & 3)) << 3);
  const int arow = wm * 128 + rb;            // + ih*64 + i*16
  const int brow = wn * 64 + rb;             // + j*16

  f32x4 acc[8][4] = {};
  const int NT = K / BK;                     // 128
  const int NG = NT / 2;                     // 64 groups of 2 tiles

  // prologue: stage tiles 0,1,2 (12 loads); vmcnt(8) -> tile 0 resident
  STAGE_A(0); STAGE_B(0);
  STAGE_A(1); STAGE_B(1);
  STAGE_A(2); STAGE_B(2);
  asm volatile("s_waitcnt vmcnt(8)" ::: "memory");
  SBAR();

  for (int g = 0; g < NG; ++g) {
    const int t0 = 2 * g, t1 = 2 * g + 1;
    const int s0 = 2 * g + 3, s1 = 2 * g + 4;  // tiles staged this group
    const u16* bufA0 = lA[t0 & 3];
    const u16* bufB0 = lB[t0 & 3];
    const u16* bufA1 = lA[t1 & 3];
    const u16* bufB1 = lB[t1 & 3];

    // ---------------- P0: tile t0, ih=0 -----------------------------------
    bf16x8 av[4], bv[4];
#pragma unroll
    for (int i = 0; i < 4; ++i)
      av[i] = *(const bf16x8*)(bufA0 + (arow + i * 16) * BK + cc);
#pragma unroll
    for (int j = 0; j < 4; ++j)
      bv[j] = *(const bf16x8*)(bufB0 + (brow + j * 16) * BK + cc);
    if (s0 < NT) STAGE_A(s0);
    SBAR();
    __builtin_amdgcn_s_setprio(1);
#pragma unroll
    for (int i = 0; i < 4; ++i)
#pragma unroll
      for (int j = 0; j < 4; ++j)
        acc[i][j] = __builtin_amdgcn_mfma_f32_16x16x32_bf16(av[i], bv[j],
                                                            acc[i][j], 0, 0, 0);
    __builtin_amdgcn_s_setprio(0);
    SBAR();

    // ---------------- P1: tile t0, ih=1 -----------------------------------
    bf16x8 aw[4];
#pragma unroll
    for (int i = 0; i < 4; ++i)
      aw[i] = *(const bf16x8*)(bufA0 + (arow + 64 + i * 16) * BK + cc);
    if (s0 < NT) STAGE_B(s0);
    SBAR();
    __builtin_amdgcn_s_setprio(1);
#pragma unroll
    for (int i = 0; i < 4; ++i)
#pragma unroll
      for (int j = 0; j < 4; ++j)
        acc[4 + i][j] = __builtin_amdgcn_mfma_f32_16x16x32_bf16(aw[i], bv[j],
                                                                acc[4 + i][j],
                                                                0, 0, 0);
    __builtin_amdgcn_s_setprio(0);
    // ensure tile t1 resident; allow the 8 youngest loads (tiles s0-1? no:
    // units after B(t1): A(t1+1),B(t1+1),A(s0),B(s0) = 8 loads) in flight.
    if (g < NG - 1) asm volatile("s_waitcnt vmcnt(8)" ::: "memory");
    else            asm volatile("s_waitcnt vmcnt(0)" ::: "memory");
    SBAR();

    // ---------------- P2: tile t1, ih=0 -----------------------------------
#pragma unroll
    for (int i = 0; i < 4; ++i)
      av[i] = *(const bf16x8*)(bufA1 + (arow + i * 16) * BK + cc);
#pragma unroll
    for (int j = 0; j < 4; ++j)
      bv[j] = *(const bf16x8*)(bufB1 + (brow + j * 16) * BK + cc);
    if (s1 < NT) STAGE_A(s1);
    SBAR();
    __builtin_amdgcn_s_setprio(1);
#pragma unroll
    for (int i = 0; i < 4; ++i)
#pragma unroll
      for (int j = 0; j < 4; ++j)
        acc[i][j] = __builtin_amdgcn_mfma_f32_16x16x32_bf16(av[i], bv[j],
                                                            acc[i][j], 0, 0, 0);
    __builtin_amdgcn_s_setprio(0);
    SBAR();

    // ---------------- P3: tile t1, ih=1 -----------------------------------
#pragma unroll
    for (int i = 0; i < 4; ++i)
      aw[i] = *(const bf16x8*)(bufA1 + (arow + 64 + i * 16) * BK + cc);
    if (s1 < NT) STAGE_B(s1);
    SBAR();
    __builtin_amdgcn_s_setprio(1);
#pragma unroll
    for (int i = 0; i < 4; ++i)
#pragma unroll
      for (int j = 0; j < 4; ++j)
        acc[4 + i][j] = __builtin_amdgcn_mfma_f32_16x16x32_bf16(aw[i], bv[j],
                                                                acc[4 + i][j],
                                                                0, 0, 0);
    __builtin_amdgcn_s_setprio(0);
    // ensure tile 2g+2 (next group's t0) resident; allow 8 youngest
    // (A(2g+3),B(2g+3),A(2g+4),B(2g+4)).
    if (g < NG - 2)       asm volatile("s_waitcnt vmcnt(8)" ::: "memory");
    else if (g == NG - 2) asm volatile("s_waitcnt vmcnt(4)" ::: "memory");
    SBAR();
  }

  // ---------------- epilogue: out = alpha*acc + bias ------------------------
  float ax = fmaxf(__uint_as_float(sc[0]), 1e-12f);
  float aw_ = fmaxf(__uint_as_float(sc[1]), 1e-12f);
  float alpha = (ax * aw_) / 7225344.0f;     // amax_x*amax_w / 2688^2

  const int orow = (lane >> 4) * 4;          // C/D: col=lane&15, row=(lane>>4)*4+reg
  const int ocol = lane & 15;
#pragma unroll
  for (int ai = 0; ai < 8; ++ai) {
#pragma unroll
    for (int j = 0; j < 4; ++j) {
      int col = tn0 + wn * 64 + j * 16 + ocol;
      float bvv = bias[col];
#pragma unroll
      for (int rr = 0; rr < 4; ++rr) {
        int row = tm0 + wm * 128 + ai * 16 + orow + rr;
        C[(size_t)row * N + col] = alpha * acc[ai][j][rr] + bvv;
      }
    }
  }
#undef STAGE_A
#undef STAGE_B
}

// ---------------------------------------------------------------------------

extern "C" void kernel_launch(void* const* d_in, const int* in_sizes, int n_in,
                              void* d_out, int out_size, void* d_ws, size_t ws_size,
                              hipStream_t stream) {
  const float* x = (const float*)d_in[0];
  const float* w = (const float*)d_in[1];
  const float* bias = (const float*)d_in[2];
  float* out = (float*)d_out;

  const int N = in_sizes[2];
  const int K = in_sizes[1] / N;
  const int M = in_sizes[0] / K;

  unsigned char* ws = (unsigned char*)d_ws;
  unsigned* sc = (unsigned*)ws;
  u16* dx = (u16*)(ws + 256);
  u16* dw = (u16*)(ws + 256 + (size_t)M * K * sizeof(u16));

  hipMemsetAsync(sc, 0, 8, stream);

  nvfp4_amax_kernel<<<dim3(256, 2), 256, 0, stream>>>(x, w, sc, M * K / 4,
                                                      N * K / 4);

  int nbx = M * K / 16, nbw = N * K / 16;
  nvfp4_quant_kernel<<<(nbx + 255) / 256, 256, 0, stream>>>(x, dx, sc, 0, nbx);
  nvfp4_quant_kernel<<<(nbw + 255) / 256, 256, 0, stream>>>(w, dw, sc, 1, nbw);

  nvfp4_gemm_kernel<<<dim3((M / BM) * (N / BN)), 512, 0, stream>>>(
      dx, dw, bias, sc, out, M, N, K);
}